// Round 19
// baseline (64.309 us; speedup 1.0000x reference)
//
#include <hip/hip_runtime.h>
#include <hip/hip_bf16.h>
#include <math.h>

typedef __attribute__((ext_vector_type(8))) __bf16 bf16x8;
typedef __attribute__((ext_vector_type(4))) float f32x4;
typedef __attribute__((ext_vector_type(16))) float f32x16;
typedef __attribute__((ext_vector_type(4))) float float4_t;
typedef __attribute__((ext_vector_type(4))) unsigned int uint4_t;

#define NB 4
#define TSEQ 4096
#define CD 1024
#define HD 64
#define NCH 8      // max KV chunks per q-block
#define CHT 8      // KV tiles (of 64) per chunk
#define QBL 16     // q-blocks per batch (256 rows each)

static __device__ __forceinline__ unsigned short f2bf(float f) {
    union { float f; unsigned u; } v; v.f = f;
    unsigned r = v.u + 0x7fffu + ((v.u >> 16) & 1u);
    return (unsigned short)(r >> 16);
}
static __device__ __forceinline__ float bf2f(unsigned short u) {
    union { unsigned int i; float f; } v; v.i = ((unsigned int)u) << 16;
    return v.f;
}
// pair pack; compiler fuses to v_cvt_pk_bf16_f32
static __device__ __forceinline__ unsigned int pk2(float a, float b) {
    union { __bf16 h[2]; unsigned int u; } x;
    x.h[0] = (__bf16)a; x.h[1] = (__bf16)b;
    return x.u;
}

// ---------------- W f32 -> bf16, permuted rows ----------------
// dest row blocks of 16: [q0,q32,q16,q48, k0,k32,k16,k48, v0,v16,v32,v48]
__global__ __launch_bounds__(256) void wcvt_kernel(const float* __restrict__ wq,
                                                   const float* __restrict__ wk,
                                                   const float* __restrict__ wv,
                                                   unsigned short* __restrict__ wb) {
    int i = blockIdx.x * 256 + threadIdx.x;   // over 192*1024
    int j = i >> 10;                          // dest row
    int col = i & 1023;
    int jb = j >> 4, off = j & 15;
    int sub = ((jb & 1) << 5) | ((jb & 2) << 3);  // 0,32,16,48
    int srcrow = (jb < 8) ? (sub + off) : ((jb - 8) * 16 + off);
    const float* src = (jb < 4) ? wq : ((jb < 8) ? wk : wv);
    wb[i] = f2bf(src[srcrow * 1024 + col]);
}

// ---------------- fused QKV projection + RoPE, ONE phase ----------------
// x read ONCE (was 3x): 512 blocks x 32 rows; all 192 permuted W rows staged
// per block (L2-resident bf16). 4 waves = (row half wr, col half wc of 96);
// each wave 16 rows x 96 cols, 12 MFMA/k-step. Epilogue = refcheck'd phase
// pairing (wc=0: q + k-hb0, sc2 folded into q; wc=1: k-hb16 + v).
__global__ __launch_bounds__(256) void qkv_kernel(const float* __restrict__ x,
                                                  const unsigned short* __restrict__ wb,
                                                  unsigned short* __restrict__ qo,
                                                  unsigned short* __restrict__ ko,
                                                  unsigned short* __restrict__ vt) {
    __shared__ unsigned short xs[32][72];
    __shared__ unsigned short ws[192][72];
    const int tid = threadIdx.x;
    const int wave = tid >> 6, lane = tid & 63;
    const int lr = lane & 15;
    const int lk = (lane >> 4) << 3;
    const int rowg = (lane >> 4) << 2;
    const int wr = wave & 1, wc = wave >> 1;
    const int row0 = blockIdx.x * 32;

    f32x4 acc[6];
#pragma unroll
    for (int i = 0; i < 6; ++i) acc[i] = (f32x4){0.f, 0.f, 0.f, 0.f};

    const int xr = tid >> 3;          // x staging: row 0..31
    const int xc = (tid & 7) << 3;    // 8 f32 -> 8 bf16

    for (int k0 = 0; k0 < CD; k0 += 64) {
        __syncthreads();
        {   // stage x tile 32x64 f32 -> bf16 (coalesced 32B/thread)
            const float4_t* s4 =
                reinterpret_cast<const float4_t*>(x + (size_t)(row0 + xr) * CD + k0 + xc);
            float4_t f0 = s4[0], f1 = s4[1];
            uint4_t w0;
            w0[0] = pk2(f0[0], f0[1]); w0[1] = pk2(f0[2], f0[3]);
            w0[2] = pk2(f1[0], f1[1]); w0[3] = pk2(f1[2], f1[3]);
            *reinterpret_cast<uint4_t*>(&xs[xr][xc]) = w0;
        }
#pragma unroll
        for (int i = 0; i < 6; ++i) {   // stage W 192x64 bf16 (6 x 16B/thread)
            int u = tid + (i << 8);
            int r = u >> 3, c8 = (u & 7) << 3;
            *reinterpret_cast<uint4_t*>(&ws[r][c8]) =
                *reinterpret_cast<const uint4_t*>(wb + (size_t)r * CD + k0 + c8);
        }
        __syncthreads();
#pragma unroll
        for (int kk = 0; kk < 2; ++kk) {
            bf16x8 a = *reinterpret_cast<const bf16x8*>(&xs[wr * 16 + lr][kk * 32 + lk]);
#pragma unroll
            for (int c = 0; c < 6; ++c) {
                bf16x8 bfr =
                    *reinterpret_cast<const bf16x8*>(&ws[wc * 96 + c * 16 + lr][kk * 32 + lk]);
                acc[c] = __builtin_amdgcn_mfma_f32_16x16x32_bf16(a, bfr, acc[c], 0, 0, 0);
            }
        }
    }

    // epilogue (refcheck'd pairing; attention scale folded into q)
    const int gr0 = row0 + wr * 16 + rowg;        // global row (b*TSEQ + t)
    const int bidx = gr0 >> 12;
    const int tb = gr0 & (TSEQ - 1);
    const float sc2 = 0.045084218764560315f;      // 1024^-0.5 * log2(e)
    const float l2b = 0.4152410118609215f;        // log2(10000)/32
    const float invf0 = exp2f(-(float)lr * l2b);
    const float invf1 = exp2f(-(float)(lr + 16) * l2b);
#pragma unroll
    for (int r = 0; r < 4; ++r) {
        float t = (float)(tb + r);
        float s0, c0, s1, c1;
        sincosf(t * invf0, &s0, &c0);
        sincosf(t * invf1, &s1, &c1);
        size_t ro = (size_t)(gr0 + r) * HD;
        if (wc == 0) {
            float lo, hi;
            lo = acc[0][r]; hi = acc[1][r];
            qo[ro + 0 + lr]  = f2bf((lo * c0 - hi * s0) * sc2);
            qo[ro + 32 + lr] = f2bf((hi * c0 + lo * s0) * sc2);
            lo = acc[2][r]; hi = acc[3][r];
            qo[ro + 16 + lr] = f2bf((lo * c1 - hi * s1) * sc2);
            qo[ro + 48 + lr] = f2bf((hi * c1 + lo * s1) * sc2);
            lo = acc[4][r]; hi = acc[5][r];
            ko[ro + 0 + lr]  = f2bf(lo * c0 - hi * s0);
            ko[ro + 32 + lr] = f2bf(hi * c0 + lo * s0);
        } else {
            float lo = acc[0][r], hi = acc[1][r];
            ko[ro + 16 + lr] = f2bf(lo * c1 - hi * s1);
            ko[ro + 48 + lr] = f2bf(hi * c1 + lo * s1);
            size_t vbase = (size_t)bidx * HD * TSEQ + (size_t)(tb + r);
            vt[vbase + (size_t)(0 + lr) * TSEQ]  = f2bf(acc[2][r]);
            vt[vbase + (size_t)(16 + lr) * TSEQ] = f2bf(acc[3][r]);
            vt[vbase + (size_t)(32 + lr) * TSEQ] = f2bf(acc[4][r]);
            vt[vbase + (size_t)(48 + lr) * TSEQ] = f2bf(acc[5][r]);
        }
    }
}

// ---------------- causal flash attention, KV-split partials ----------------
// R15-exact (best build). 8 waves share one staged KV tile; QBLK=256; CHT=8.
// 32x32 swapped S^T = mfma(K,Q); O^T = mfma(V^T,P^T); tree reductions;
// defer-max THR=7; setprio. po layout: bf16 [slot][d 64][q 256].
__global__ __launch_bounds__(512, 4) void attn_partial(const unsigned short* __restrict__ q,
                                                       const unsigned short* __restrict__ k,
                                                       const unsigned short* __restrict__ vt,
                                                       unsigned short* __restrict__ po,
                                                       float* __restrict__ pm,
                                                       float* __restrict__ pl) {
    const int chunk = blockIdx.x, qb = blockIdx.y, b = blockIdx.z;
    const int ktend_blk = 4 * qb + 3;        // last KV tile any wave needs
    const int kt0 = chunk * CHT;
    if (kt0 > ktend_blk) return;
    const int ktend = min(ktend_blk, kt0 + CHT - 1);

    __shared__ unsigned short ks[64][72];
    __shared__ unsigned short vs[64][72];
    const int tid = threadIdx.x;
    const int wave = tid >> 6, lane = tid & 63;
    const int l31 = lane & 31;
    const int h = lane >> 5;           // lane half
    const int h8 = h << 3;
    const int qrow0 = qb * 256 + wave * 32;  // this wave's q base (within batch)
    const int qpos = qrow0 + l31;            // q row owned by this lane

    // Q fragments (scale pre-folded at qkv): qf[s] = Q[qpos][16s + h8 .. +7]
    const unsigned short* qb_ = q + ((size_t)(b * TSEQ + qpos)) * HD + h8;
    bf16x8 qf[4];
#pragma unroll
    for (int s = 0; s < 4; ++s)
        qf[s] = *reinterpret_cast<const bf16x8*>(qb_ + 16 * s);

    f32x16 oacc[2];   // O^T tiles: row d = 32*dt + crow(r,h), col q = l31
#pragma unroll
    for (int dt = 0; dt < 2; ++dt)
#pragma unroll
        for (int r = 0; r < 16; ++r) oacc[dt][r] = 0.f;
    float mreg = -1.0e30f;   // log2-domain running max (finite: empty-wave safe)
    float lsum = 0.f;

    // staging: 512 threads cover K tile (8KB) + V tile (8KB), 16B each
    const int srow = tid >> 3;           // 0..63
    const int scol = (tid & 7) << 3;     // 0..56 step 8 (elements)
    const unsigned short* kbase = k + (size_t)b * TSEQ * HD;
    const unsigned short* vbase = vt + (size_t)b * HD * TSEQ;
    uint4_t kr, vr;

    auto loadtile = [&](int kt) {
        const int s0l = kt * 64;
        kr = *reinterpret_cast<const uint4_t*>(kbase + (size_t)(s0l + srow) * HD + scol);
        vr = *reinterpret_cast<const uint4_t*>(vbase + (size_t)srow * TSEQ + s0l + scol);
    };

    loadtile(kt0);

    for (int kt = kt0; kt <= ktend; ++kt) {
        const int s0 = kt * 64;
        __syncthreads();
        *reinterpret_cast<uint4_t*>(&ks[srow][scol]) = kr;
        *reinterpret_cast<uint4_t*>(&vs[srow][scol]) = vr;
        __syncthreads();
        if (kt < ktend) loadtile(kt + 1);   // prefetch under compute

        if (s0 > qrow0 + 31) continue;      // wave fully above diagonal

        // S^T = K Q^T : two 32x32 C-tiles (kv blocks 0-31, 32-63)
        f32x16 sacc[2];
#pragma unroll
        for (int blk = 0; blk < 2; ++blk)
#pragma unroll
            for (int r = 0; r < 16; ++r) sacc[blk][r] = 0.f;
        __builtin_amdgcn_s_setprio(1);
#pragma unroll
        for (int s = 0; s < 4; ++s) {
            bf16x8 ka = *reinterpret_cast<const bf16x8*>(&ks[l31][16 * s + h8]);
            bf16x8 kb2 = *reinterpret_cast<const bf16x8*>(&ks[32 + l31][16 * s + h8]);
            sacc[0] = __builtin_amdgcn_mfma_f32_32x32x16_bf16(ka, qf[s], sacc[0], 0, 0, 0);
            sacc[1] = __builtin_amdgcn_mfma_f32_32x32x16_bf16(kb2, qf[s], sacc[1], 0, 0, 0);
        }
        __builtin_amdgcn_s_setprio(0);

        if (s0 + 63 > qrow0) {   // tile straddles this wave's diagonal: mask
#pragma unroll
            for (int blk = 0; blk < 2; ++blk)
#pragma unroll
                for (int r = 0; r < 16; ++r) {
                    int kvpos = s0 + 32 * blk + (r & 3) + ((r >> 2) << 3) + (h << 2);
                    if (kvpos > qpos) sacc[blk][r] = -INFINITY;
                }
        }

        // row max: pairwise tree + 1 shfl
        float tm[8];
#pragma unroll
        for (int r = 0; r < 8; ++r)
            tm[r] = fmaxf(fmaxf(sacc[0][r], sacc[0][r + 8]),
                          fmaxf(sacc[1][r], sacc[1][r + 8]));
#pragma unroll
        for (int r = 0; r < 4; ++r) tm[r] = fmaxf(tm[r], tm[r + 4]);
        float mx = fmaxf(fmaxf(tm[0], tm[1]), fmaxf(tm[2], tm[3]));
        mx = fmaxf(mx, __shfl_xor(mx, 32, 64));

        // defer-max: rescale only when max grew by more than THR=7 (P <= 2^7)
        const bool newmax = !__all(mx <= mreg + 7.0f);
        if (newmax) {
            float mnew = fmaxf(mreg, mx);
            float corr = __builtin_amdgcn_exp2f(mreg - mnew);
            mreg = mnew;
            lsum *= corr;
#pragma unroll
            for (int dt = 0; dt < 2; ++dt)
#pragma unroll
                for (int r = 0; r < 16; ++r) oacc[dt][r] *= corr;
        }

        // exp + tree row-sum
        float pvv[2][16];
#pragma unroll
        for (int blk = 0; blk < 2; ++blk)
#pragma unroll
            for (int r = 0; r < 16; ++r)
                pvv[blk][r] = __builtin_amdgcn_exp2f(sacc[blk][r] - mreg);
        float ts[8];
#pragma unroll
        for (int r = 0; r < 8; ++r)
            ts[r] = (pvv[0][r] + pvv[0][r + 8]) + (pvv[1][r] + pvv[1][r + 8]);
#pragma unroll
        for (int r = 0; r < 4; ++r) ts[r] += ts[r + 4];
        float psum = (ts[0] + ts[1]) + (ts[2] + ts[3]);
        psum += __shfl_xor(psum, 32, 64);
        lsum += psum;

        // pack P rows to bf16 pair-words
        unsigned int cw[2][4][2];
#pragma unroll
        for (int blk = 0; blk < 2; ++blk)
#pragma unroll
            for (int G = 0; G < 4; ++G) {
                cw[blk][G][0] = pk2(pvv[blk][4 * G], pvv[blk][4 * G + 1]);
                cw[blk][G][1] = pk2(pvv[blk][4 * G + 2], pvv[blk][4 * G + 3]);
            }

        // P^T B-frags per k-slot (2 shfl_xor(32) each) + PV MFMAs
        const bool hif = (h == 1);
        __builtin_amdgcn_s_setprio(1);
#pragma unroll
        for (int s = 0; s < 4; ++s) {
            const int blk = s >> 1, base = (s & 1) << 1;
            unsigned int a0 = cw[blk][base][0],     a1 = cw[blk][base][1];
            unsigned int b0 = cw[blk][base + 1][0], b1 = cw[blk][base + 1][1];
            unsigned int s0w = hif ? a0 : b0;
            unsigned int s1w = hif ? a1 : b1;
            unsigned int r0 = __shfl_xor(s0w, 32, 64);
            unsigned int r1 = __shfl_xor(s1w, 32, 64);
            uint4_t pw;
            pw[0] = hif ? r0 : a0;
            pw[1] = hif ? r1 : a1;
            pw[2] = hif ? b0 : r0;
            pw[3] = hif ? b1 : r1;
            bf16x8 pfrag = *reinterpret_cast<const bf16x8*>(&pw);
            bf16x8 v0 = *reinterpret_cast<const bf16x8*>(&vs[l31][16 * s + h8]);
            bf16x8 v1 = *reinterpret_cast<const bf16x8*>(&vs[32 + l31][16 * s + h8]);
            oacc[0] = __builtin_amdgcn_mfma_f32_32x32x16_bf16(v0, pfrag, oacc[0], 0, 0, 0);
            oacc[1] = __builtin_amdgcn_mfma_f32_32x32x16_bf16(v1, pfrag, oacc[1], 0, 0, 0);
        }
        __builtin_amdgcn_s_setprio(0);
    }

    // write transposed partial bf16 [d][q256] + (m2, l)
    const int slot = (((b << 4) + qb) << 3) + chunk;
    unsigned short* pob = po + (size_t)slot * 16384;
#pragma unroll
    for (int dt = 0; dt < 2; ++dt)
#pragma unroll
        for (int r = 0; r < 16; ++r) {
            int d = 32 * dt + (r & 3) + ((r >> 2) << 3) + (h << 2);
            pob[d * 256 + wave * 32 + l31] = f2bf(oacc[dt][r]);
        }
    if (h == 0) {
        pm[slot * 256 + wave * 32 + l31] = mreg;
        pl[slot * 256 + wave * 32 + l31] = lsum;
    }
}

// ---------------- combine partials (po bf16 [slot][d][q256]) ----------------
// R15-exact. grid (bq=256, dg=4). Parallel masked pm loads + register tree max.
__global__ __launch_bounds__(256) void attn_combine(const unsigned short* __restrict__ po,
                                                    const float* __restrict__ pm,
                                                    const float* __restrict__ pl,
                                                    float* __restrict__ out) {
    __shared__ float sm[64][17];
    const int bq = blockIdx.x;       // b*64 + qt  (qt = 4*qb + quarter)
    const int dg = blockIdx.y;       // 16-d group
    const int qt = bq & 63;
    const int b = bq >> 6;
    const int qb = qt >> 2, quarter = qt & 3;
    const int nch = (4 * qb + 11) >> 3;  // ceil((4qb+4)/8), CHT=8
    const int qi = threadIdx.x & 63;
    const int jj = threadIdx.x >> 6;     // wave index -> 4 d-cols
    const int slotb = (((b << 4) + qb) << 3);
    const int qoff = quarter * 64 + qi;

    // parallel masked pm loads + register tree max
    float pmv[NCH];
#pragma unroll
    for (int c = 0; c < NCH; ++c)
        pmv[c] = (c < nch) ? pm[(size_t)(slotb + c) * 256 + qoff] : -1.0e30f;
    float tmv[NCH];
#pragma unroll
    for (int c = 0; c < NCH; ++c) tmv[c] = pmv[c];
#pragma unroll
    for (int s = NCH / 2; s >= 1; s >>= 1)
#pragma unroll
        for (int c = 0; c < NCH / 2; ++c)
            if (c < s) tmv[c] = fmaxf(tmv[c], tmv[c + s]);
    const float M = tmv[0];

    float L = 0.f;
    float a0 = 0.f, a1 = 0.f, a2 = 0.f, a3 = 0.f;
    const int dbase = dg * 16 + jj * 4;
#pragma unroll 4
    for (int c = 0; c < nch; ++c) {
        float w = exp2f(pmv[c] - M);
        L += w * pl[(size_t)(slotb + c) * 256 + qoff];
        const unsigned short* p = po + (size_t)(slotb + c) * 16384 + dbase * 256 + qoff;
        a0 += w * bf2f(p[0]);
        a1 += w * bf2f(p[256]);
        a2 += w * bf2f(p[512]);
        a3 += w * bf2f(p[768]);
    }
    const float inv = 1.f / L;
    sm[qi][jj * 4 + 0] = a0 * inv;
    sm[qi][jj * 4 + 1] = a1 * inv;
    sm[qi][jj * 4 + 2] = a2 * inv;
    sm[qi][jj * 4 + 3] = a3 * inv;
    __syncthreads();
    // coalesced out write: thread t -> q-row t>>2, 4-col chunk (t&3)
    const int row = threadIdx.x >> 2;
    const int c4 = (threadIdx.x & 3) << 2;
    float4_t f;
#pragma unroll
    for (int e = 0; e < 4; ++e) f[e] = sm[row][c4 + e];
    *reinterpret_cast<float4_t*>(out + (size_t)bq * 4096 + row * 64 + dg * 16 + c4) = f;
}

extern "C" void kernel_launch(void* const* d_in, const int* in_sizes, int n_in,
                              void* d_out, int out_size, void* d_ws, size_t ws_size,
                              hipStream_t stream) {
    const float* x = (const float*)d_in[0];
    const float* wq = (const float*)d_in[1];
    const float* wk = (const float*)d_in[2];
    const float* wv = (const float*)d_in[3];
    float* out = (float*)d_out;

    unsigned short* wb = (unsigned short*)d_ws;               // 192*1024 bf16
    unsigned short* qb = wb + 3 * HD * CD;
    unsigned short* kb = qb + (size_t)NB * TSEQ * HD;
    unsigned short* vtb = kb + (size_t)NB * TSEQ * HD;
    unsigned short* pob = vtb + (size_t)NB * TSEQ * HD;       // 512 slots * 16384 bf16
    float* pm = (float*)(pob + (size_t)512 * 16384);          // 512 * 256 f32
    float* pl = pm + (size_t)512 * 256;

    wcvt_kernel<<<768, 256, 0, stream>>>(wq, wk, wv, wb);
    qkv_kernel<<<512, 256, 0, stream>>>(x, wb, qb, kb, vtb);
    attn_partial<<<dim3(NCH, QBL, NB), 512, 0, stream>>>(qb, kb, vtb, pob, pm, pl);
    attn_combine<<<dim3(NB * 64, 4), 256, 0, stream>>>(pob, pm, pl, out);
}

// Round 20
// 61.253 us; speedup vs baseline: 1.0499x; 1.0499x over previous
//
#include <hip/hip_runtime.h>
#include <hip/hip_bf16.h>
#include <math.h>

typedef __attribute__((ext_vector_type(8))) __bf16 bf16x8;
typedef __attribute__((ext_vector_type(4))) float f32x4;
typedef __attribute__((ext_vector_type(16))) float f32x16;
typedef __attribute__((ext_vector_type(4))) float float4_t;
typedef __attribute__((ext_vector_type(4))) unsigned int uint4_t;

#define NB 4
#define TSEQ 4096
#define CD 1024
#define HD 64
#define NCH 8      // max KV chunks per q-block
#define CHT 8      // KV tiles (of 64) per chunk
#define QBL 16     // q-blocks per batch (256 rows each)

static __device__ __forceinline__ unsigned short f2bf(float f) {
    union { float f; unsigned u; } v; v.f = f;
    unsigned r = v.u + 0x7fffu + ((v.u >> 16) & 1u);
    return (unsigned short)(r >> 16);
}
static __device__ __forceinline__ float bf2f(unsigned short u) {
    union { unsigned int i; float f; } v; v.i = ((unsigned int)u) << 16;
    return v.f;
}
// pair pack; compiler fuses to v_cvt_pk_bf16_f32
static __device__ __forceinline__ unsigned int pk2(float a, float b) {
    union { __bf16 h[2]; unsigned int u; } x;
    x.h[0] = (__bf16)a; x.h[1] = (__bf16)b;
    return x.u;
}

// ---------------- W f32 -> bf16, permuted rows ----------------
// dest row blocks of 16: [q0,q32,q16,q48, k0,k32,k16,k48, v0,v16,v32,v48]
__global__ __launch_bounds__(256) void wcvt_kernel(const float* __restrict__ wq,
                                                   const float* __restrict__ wk,
                                                   const float* __restrict__ wv,
                                                   unsigned short* __restrict__ wb) {
    int i = blockIdx.x * 256 + threadIdx.x;   // over 192*1024
    int j = i >> 10;                          // dest row
    int col = i & 1023;
    int jb = j >> 4, off = j & 15;
    int sub = ((jb & 1) << 5) | ((jb & 2) << 3);  // 0,32,16,48
    int srcrow = (jb < 8) ? (sub + off) : ((jb - 8) * 16 + off);
    const float* src = (jb < 4) ? wq : ((jb < 8) ? wk : wv);
    wb[i] = f2bf(src[srcrow * 1024 + col]);
}

// ---------------- fused QKV projection + RoPE (LDS-staged, 64x64 tiles) ----
// grid dim3(256,3): proven ordering (W tile stays hot in L2 per col-phase).
__global__ __launch_bounds__(256) void qkv_kernel(const float* __restrict__ x,
                                                  const unsigned short* __restrict__ wb,
                                                  unsigned short* __restrict__ qo,
                                                  unsigned short* __restrict__ ko,
                                                  unsigned short* __restrict__ vt) {
    __shared__ unsigned short xs[64][72];
    __shared__ unsigned short ws[64][72];
    const int tid = threadIdx.x;
    const int wave = tid >> 6, lane = tid & 63;
    const int lr = lane & 15;
    const int lk = (lane >> 4) << 3;
    const int rowg = (lane >> 4) << 2;
    const int row0 = blockIdx.x * 64;
    const int cbi = blockIdx.y;
    const int cb = cbi * 64;          // permuted W row block (0=q, 64=k, 128=v)

    f32x4 acc[4];
#pragma unroll
    for (int i = 0; i < 4; ++i) acc[i] = (f32x4){0.f, 0.f, 0.f, 0.f};

    const int sr = tid >> 2;          // staging row 0..63
    const int sc = (tid & 3) << 4;    // staging col (elements)

    for (int k0 = 0; k0 < CD; k0 += 64) {
        __syncthreads();
        {   // stage x tile 64x64 f32 -> bf16 via cvt_pk (coalesced 64B/thread)
            const float4_t* s4 =
                reinterpret_cast<const float4_t*>(x + (size_t)(row0 + sr) * CD + k0 + sc);
            float4_t f0 = s4[0], f1 = s4[1], f2 = s4[2], f3 = s4[3];
            uint4_t w0, w1;
            w0[0] = pk2(f0[0], f0[1]); w0[1] = pk2(f0[2], f0[3]);
            w0[2] = pk2(f1[0], f1[1]); w0[3] = pk2(f1[2], f1[3]);
            w1[0] = pk2(f2[0], f2[1]); w1[1] = pk2(f2[2], f2[3]);
            w1[2] = pk2(f3[0], f3[1]); w1[3] = pk2(f3[2], f3[3]);
            *reinterpret_cast<uint4_t*>(&xs[sr][sc]) = w0;
            *reinterpret_cast<uint4_t*>(&xs[sr][sc + 8]) = w1;
        }
        {   // stage W tile 64x64 bf16 (coalesced 32B/thread)
            const uint4_t* wsrc =
                reinterpret_cast<const uint4_t*>(wb + (size_t)(cb + sr) * CD + k0 + sc);
            *reinterpret_cast<uint4_t*>(&ws[sr][sc]) = wsrc[0];
            *reinterpret_cast<uint4_t*>(&ws[sr][sc + 8]) = wsrc[1];
        }
        __syncthreads();
#pragma unroll
        for (int kk = 0; kk < 2; ++kk) {
            bf16x8 a = *reinterpret_cast<const bf16x8*>(&xs[wave * 16 + lr][kk * 32 + lk]);
#pragma unroll
            for (int c = 0; c < 4; ++c) {
                bf16x8 bfr = *reinterpret_cast<const bf16x8*>(&ws[c * 16 + lr][kk * 32 + lk]);
                acc[c] = __builtin_amdgcn_mfma_f32_16x16x32_bf16(a, bfr, acc[c], 0, 0, 0);
            }
        }
    }

    const int gr0 = row0 + wave * 16 + rowg;      // global row (b*TSEQ + t)
    const int bidx = gr0 >> 12;
    const int tb = gr0 & (TSEQ - 1);
    if (cbi < 2) {
        unsigned short* o = (cbi == 0) ? qo : ko;
        // fold attention scale (1/32 * log2(e)) into q only
        const float sc2 = (cbi == 0) ? 0.045084218764560315f : 1.0f;
        const float l2b = 0.4152410118609215f;    // log2(10000)/32
        const float invf0 = exp2f(-(float)lr * l2b);
        const float invf1 = exp2f(-(float)(lr + 16) * l2b);
#pragma unroll
        for (int r = 0; r < 4; ++r) {
            float t = (float)(tb + r);
            float s0, c0, s1, c1;
            sincosf(t * invf0, &s0, &c0);
            sincosf(t * invf1, &s1, &c1);
            size_t ro = (size_t)(gr0 + r) * HD;
            float lo, hi;
            lo = acc[0][r]; hi = acc[1][r];
            o[ro + 0 + lr]  = f2bf((lo * c0 - hi * s0) * sc2);
            o[ro + 32 + lr] = f2bf((hi * c0 + lo * s0) * sc2);
            lo = acc[2][r]; hi = acc[3][r];
            o[ro + 16 + lr] = f2bf((lo * c1 - hi * s1) * sc2);
            o[ro + 48 + lr] = f2bf((hi * c1 + lo * s1) * sc2);
        }
    } else {
#pragma unroll
        for (int r = 0; r < 4; ++r) {
            size_t vbase = (size_t)bidx * HD * TSEQ + (size_t)(tb + r);
            vt[vbase + (size_t)(0 + lr) * TSEQ]  = f2bf(acc[0][r]);
            vt[vbase + (size_t)(16 + lr) * TSEQ] = f2bf(acc[1][r]);
            vt[vbase + (size_t)(32 + lr) * TSEQ] = f2bf(acc[2][r]);
            vt[vbase + (size_t)(48 + lr) * TSEQ] = f2bf(acc[3][r]);
        }
    }
}

// ---------------- causal flash attention, KV-split partials ----------------
// 8 waves share one staged KV tile; QBLK=256 (8 x 32 q-rows). Proven per-wave
// inner loop (32x32 swapped S^T = mfma(K,Q); O^T = mfma(V^T,P^T); tree
// reductions; defer-max THR=7; setprio). CHT=8 tiles per chunk.
// po layout: bf16 [slot][d 64][q 256].
__global__ __launch_bounds__(512, 4) void attn_partial(const unsigned short* __restrict__ q,
                                                       const unsigned short* __restrict__ k,
                                                       const unsigned short* __restrict__ vt,
                                                       unsigned short* __restrict__ po,
                                                       float* __restrict__ pm,
                                                       float* __restrict__ pl) {
    const int chunk = blockIdx.x, qb = blockIdx.y, b = blockIdx.z;
    const int ktend_blk = 4 * qb + 3;        // last KV tile any wave needs
    const int kt0 = chunk * CHT;
    if (kt0 > ktend_blk) return;
    const int ktend = min(ktend_blk, kt0 + CHT - 1);

    __shared__ unsigned short ks[64][72];
    __shared__ unsigned short vs[64][72];
    const int tid = threadIdx.x;
    const int wave = tid >> 6, lane = tid & 63;
    const int l31 = lane & 31;
    const int h = lane >> 5;           // lane half
    const int h8 = h << 3;
    const int qrow0 = qb * 256 + wave * 32;  // this wave's q base (within batch)
    const int qpos = qrow0 + l31;            // q row owned by this lane

    // Q fragments (scale pre-folded at qkv): qf[s] = Q[qpos][16s + h8 .. +7]
    const unsigned short* qb_ = q + ((size_t)(b * TSEQ + qpos)) * HD + h8;
    bf16x8 qf[4];
#pragma unroll
    for (int s = 0; s < 4; ++s)
        qf[s] = *reinterpret_cast<const bf16x8*>(qb_ + 16 * s);

    f32x16 oacc[2];   // O^T tiles: row d = 32*dt + crow(r,h), col q = l31
#pragma unroll
    for (int dt = 0; dt < 2; ++dt)
#pragma unroll
        for (int r = 0; r < 16; ++r) oacc[dt][r] = 0.f;
    float mreg = -1.0e30f;   // log2-domain running max (finite: empty-wave safe)
    float lsum = 0.f;

    // staging: 512 threads cover K tile (8KB) + V tile (8KB), 16B each
    const int srow = tid >> 3;           // 0..63
    const int scol = (tid & 7) << 3;     // 0..56 step 8 (elements)
    const unsigned short* kbase = k + (size_t)b * TSEQ * HD;
    const unsigned short* vbase = vt + (size_t)b * HD * TSEQ;
    uint4_t kr, vr;

    auto loadtile = [&](int kt) {
        const int s0l = kt * 64;
        kr = *reinterpret_cast<const uint4_t*>(kbase + (size_t)(s0l + srow) * HD + scol);
        vr = *reinterpret_cast<const uint4_t*>(vbase + (size_t)srow * TSEQ + s0l + scol);
    };

    loadtile(kt0);

    for (int kt = kt0; kt <= ktend; ++kt) {
        const int s0 = kt * 64;
        __syncthreads();
        *reinterpret_cast<uint4_t*>(&ks[srow][scol]) = kr;
        *reinterpret_cast<uint4_t*>(&vs[srow][scol]) = vr;
        __syncthreads();
        if (kt < ktend) loadtile(kt + 1);   // prefetch under compute

        if (s0 > qrow0 + 31) continue;      // wave fully above diagonal

        // S^T = K Q^T : two 32x32 C-tiles (kv blocks 0-31, 32-63)
        f32x16 sacc[2];
#pragma unroll
        for (int blk = 0; blk < 2; ++blk)
#pragma unroll
            for (int r = 0; r < 16; ++r) sacc[blk][r] = 0.f;
        __builtin_amdgcn_s_setprio(1);
#pragma unroll
        for (int s = 0; s < 4; ++s) {
            bf16x8 ka = *reinterpret_cast<const bf16x8*>(&ks[l31][16 * s + h8]);
            bf16x8 kb2 = *reinterpret_cast<const bf16x8*>(&ks[32 + l31][16 * s + h8]);
            sacc[0] = __builtin_amdgcn_mfma_f32_32x32x16_bf16(ka, qf[s], sacc[0], 0, 0, 0);
            sacc[1] = __builtin_amdgcn_mfma_f32_32x32x16_bf16(kb2, qf[s], sacc[1], 0, 0, 0);
        }
        __builtin_amdgcn_s_setprio(0);

        if (s0 + 63 > qrow0) {   // tile straddles this wave's diagonal: mask
#pragma unroll
            for (int blk = 0; blk < 2; ++blk)
#pragma unroll
                for (int r = 0; r < 16; ++r) {
                    int kvpos = s0 + 32 * blk + (r & 3) + ((r >> 2) << 3) + (h << 2);
                    if (kvpos > qpos) sacc[blk][r] = -INFINITY;
                }
        }

        // row max: pairwise tree + 1 shfl
        float tm[8];
#pragma unroll
        for (int r = 0; r < 8; ++r)
            tm[r] = fmaxf(fmaxf(sacc[0][r], sacc[0][r + 8]),
                          fmaxf(sacc[1][r], sacc[1][r + 8]));
#pragma unroll
        for (int r = 0; r < 4; ++r) tm[r] = fmaxf(tm[r], tm[r + 4]);
        float mx = fmaxf(fmaxf(tm[0], tm[1]), fmaxf(tm[2], tm[3]));
        mx = fmaxf(mx, __shfl_xor(mx, 32, 64));

        // defer-max: rescale only when max grew by more than THR=7 (P <= 2^7)
        const bool newmax = !__all(mx <= mreg + 7.0f);
        if (newmax) {
            float mnew = fmaxf(mreg, mx);
            float corr = __builtin_amdgcn_exp2f(mreg - mnew);
            mreg = mnew;
            lsum *= corr;
#pragma unroll
            for (int dt = 0; dt < 2; ++dt)
#pragma unroll
                for (int r = 0; r < 16; ++r) oacc[dt][r] *= corr;
        }

        // exp + tree row-sum
        float pvv[2][16];
#pragma unroll
        for (int blk = 0; blk < 2; ++blk)
#pragma unroll
            for (int r = 0; r < 16; ++r)
                pvv[blk][r] = __builtin_amdgcn_exp2f(sacc[blk][r] - mreg);
        float ts[8];
#pragma unroll
        for (int r = 0; r < 8; ++r)
            ts[r] = (pvv[0][r] + pvv[0][r + 8]) + (pvv[1][r] + pvv[1][r + 8]);
#pragma unroll
        for (int r = 0; r < 4; ++r) ts[r] += ts[r + 4];
        float psum = (ts[0] + ts[1]) + (ts[2] + ts[3]);
        psum += __shfl_xor(psum, 32, 64);
        lsum += psum;

        // pack P rows to bf16 pair-words
        unsigned int cw[2][4][2];
#pragma unroll
        for (int blk = 0; blk < 2; ++blk)
#pragma unroll
            for (int G = 0; G < 4; ++G) {
                cw[blk][G][0] = pk2(pvv[blk][4 * G], pvv[blk][4 * G + 1]);
                cw[blk][G][1] = pk2(pvv[blk][4 * G + 2], pvv[blk][4 * G + 3]);
            }

        // P^T B-frags per k-slot (2 shfl_xor(32) each) + PV MFMAs
        const bool hif = (h == 1);
        __builtin_amdgcn_s_setprio(1);
#pragma unroll
        for (int s = 0; s < 4; ++s) {
            const int blk = s >> 1, base = (s & 1) << 1;
            unsigned int a0 = cw[blk][base][0],     a1 = cw[blk][base][1];
            unsigned int b0 = cw[blk][base + 1][0], b1 = cw[blk][base + 1][1];
            unsigned int s0w = hif ? a0 : b0;
            unsigned int s1w = hif ? a1 : b1;
            unsigned int r0 = __shfl_xor(s0w, 32, 64);
            unsigned int r1 = __shfl_xor(s1w, 32, 64);
            uint4_t pw;
            pw[0] = hif ? r0 : a0;
            pw[1] = hif ? r1 : a1;
            pw[2] = hif ? b0 : r0;
            pw[3] = hif ? b1 : r1;
            bf16x8 pfrag = *reinterpret_cast<const bf16x8*>(&pw);
            bf16x8 v0 = *reinterpret_cast<const bf16x8*>(&vs[l31][16 * s + h8]);
            bf16x8 v1 = *reinterpret_cast<const bf16x8*>(&vs[32 + l31][16 * s + h8]);
            oacc[0] = __builtin_amdgcn_mfma_f32_32x32x16_bf16(v0, pfrag, oacc[0], 0, 0, 0);
            oacc[1] = __builtin_amdgcn_mfma_f32_32x32x16_bf16(v1, pfrag, oacc[1], 0, 0, 0);
        }
        __builtin_amdgcn_s_setprio(0);
    }

    // write transposed partial bf16 [d][q256] + (m2, l)
    const int slot = (((b << 4) + qb) << 3) + chunk;
    unsigned short* pob = po + (size_t)slot * 16384;
#pragma unroll
    for (int dt = 0; dt < 2; ++dt)
#pragma unroll
        for (int r = 0; r < 16; ++r) {
            int d = 32 * dt + (r & 3) + ((r >> 2) << 3) + (h << 2);
            pob[d * 256 + wave * 32 + l31] = f2bf(oacc[dt][r]);
        }
    if (h == 0) {
        pm[slot * 256 + wave * 32 + l31] = mreg;
        pl[slot * 256 + wave * 32 + l31] = lsum;
    }
}

// ---------------- combine partials (po bf16 [slot][d][q256]) ----------------
// grid (bq=256, dg=4). Parallel masked pm loads + register tree max.
__global__ __launch_bounds__(256) void attn_combine(const unsigned short* __restrict__ po,
                                                    const float* __restrict__ pm,
                                                    const float* __restrict__ pl,
                                                    float* __restrict__ out) {
    __shared__ float sm[64][17];
    const int bq = blockIdx.x;       // b*64 + qt  (qt = 4*qb + quarter)
    const int dg = blockIdx.y;       // 16-d group
    const int qt = bq & 63;
    const int b = bq >> 6;
    const int qb = qt >> 2, quarter = qt & 3;
    const int nch = (4 * qb + 11) >> 3;  // ceil((4qb+4)/8), CHT=8
    const int qi = threadIdx.x & 63;
    const int jj = threadIdx.x >> 6;     // wave index -> 4 d-cols
    const int slotb = (((b << 4) + qb) << 3);
    const int qoff = quarter * 64 + qi;

    // parallel masked pm loads + register tree max
    float pmv[NCH];
#pragma unroll
    for (int c = 0; c < NCH; ++c)
        pmv[c] = (c < nch) ? pm[(size_t)(slotb + c) * 256 + qoff] : -1.0e30f;
    float tmv[NCH];
#pragma unroll
    for (int c = 0; c < NCH; ++c) tmv[c] = pmv[c];
#pragma unroll
    for (int s = NCH / 2; s >= 1; s >>= 1)
#pragma unroll
        for (int c = 0; c < NCH / 2; ++c)
            if (c < s) tmv[c] = fmaxf(tmv[c], tmv[c + s]);
    const float M = tmv[0];

    float L = 0.f;
    float a0 = 0.f, a1 = 0.f, a2 = 0.f, a3 = 0.f;
    const int dbase = dg * 16 + jj * 4;
#pragma unroll 4
    for (int c = 0; c < nch; ++c) {
        float w = exp2f(pmv[c] - M);
        L += w * pl[(size_t)(slotb + c) * 256 + qoff];
        const unsigned short* p = po + (size_t)(slotb + c) * 16384 + dbase * 256 + qoff;
        a0 += w * bf2f(p[0]);
        a1 += w * bf2f(p[256]);
        a2 += w * bf2f(p[512]);
        a3 += w * bf2f(p[768]);
    }
    const float inv = 1.f / L;
    sm[qi][jj * 4 + 0] = a0 * inv;
    sm[qi][jj * 4 + 1] = a1 * inv;
    sm[qi][jj * 4 + 2] = a2 * inv;
    sm[qi][jj * 4 + 3] = a3 * inv;
    __syncthreads();
    // coalesced out write: thread t -> q-row t>>2, 4-col chunk (t&3)
    const int row = threadIdx.x >> 2;
    const int c4 = (threadIdx.x & 3) << 2;
    float4_t f;
#pragma unroll
    for (int e = 0; e < 4; ++e) f[e] = sm[row][c4 + e];
    *reinterpret_cast<float4_t*>(out + (size_t)bq * 4096 + row * 64 + dg * 16 + c4) = f;
}

extern "C" void kernel_launch(void* const* d_in, const int* in_sizes, int n_in,
                              void* d_out, int out_size, void* d_ws, size_t ws_size,
                              hipStream_t stream) {
    const float* x = (const float*)d_in[0];
    const float* wq = (const float*)d_in[1];
    const float* wk = (const float*)d_in[2];
    const float* wv = (const float*)d_in[3];
    float* out = (float*)d_out;

    unsigned short* wb = (unsigned short*)d_ws;               // 192*1024 bf16
    unsigned short* qb = wb + 3 * HD * CD;
    unsigned short* kb = qb + (size_t)NB * TSEQ * HD;
    unsigned short* vtb = kb + (size_t)NB * TSEQ * HD;
    unsigned short* pob = vtb + (size_t)NB * TSEQ * HD;       // 512 slots * 16384 bf16
    float* pm = (float*)(pob + (size_t)512 * 16384);          // 512 * 256 f32
    float* pl = pm + (size_t)512 * 256;

    wcvt_kernel<<<768, 256, 0, stream>>>(wq, wk, wv, wb);
    qkv_kernel<<<dim3(256, 3), 256, 0, stream>>>(x, wb, qb, kb, vtb);
    attn_partial<<<dim3(NCH, QBL, NB), 512, 0, stream>>>(qb, kb, vtb, pob, pm, pl);
    attn_combine<<<dim3(NB * 64, 4), 256, 0, stream>>>(pob, pm, pl, out);
}